// Round 3
// baseline (1390.781 us; speedup 1.0000x reference)
//
#include <hip/hip_runtime.h>
#include <math.h>

#define CH 64
#define HH 128
#define WW 128
#define HW 16384
#define NVALS 131072.f

// ws layout (floats):
//  weff2: ((g*64+c)*9+k)*27 + j   62208 floats  (offset-conv weights, s-summed, per-group 27 ch)
//  bias2: g*27 + j                  108 floats
//  wT:    g*36864 + c*576 + k*64+o 147456 floats (dcn weights transposed)
//  stats: sum[64] sumsq[64] a[64] b[64]  256 floats
#define WEFF2 0
#define BIAS2 62208
#define WTOFF 62464
#define STATS 209920

__device__ __forceinline__ int off_chan(int g, int j) {
    // j<18: interleaved dy/dx channels for group g; j>=18: mask channels
    return (j < 18) ? (g * 18 + j) : (72 + g * 9 + (j - 18));
}

__global__ void prep(const float* __restrict__ w_offset, const float* __restrict__ b_offset,
                     const float* __restrict__ w_dcn, float* __restrict__ ws) {
    int tid = blockIdx.x * 256 + threadIdx.x;
    if (tid < 147456) {  // dcn weight transpose
        int o = tid & 63;
        int k = (tid >> 6) % 9;
        int c = (tid / 576) & 63;
        int g = tid / 36864;
        ws[WTOFF + tid] = w_dcn[((g * 64 + o) * 64 + c) * 9 + k];
    }
    if (tid < 62208) {   // offset-conv weights: sum over the 4 tiled copies
        int j = tid % 27;
        int r = tid / 27;       // (g*64+c)*9 + k
        int k = r % 9;
        int gc = r / 9;
        int c = gc & 63;
        int g = gc >> 6;
        int o = off_chan(g, j);
        float s = 0.f;
#pragma unroll
        for (int ss = 0; ss < 4; ++ss)
            s += w_offset[(o * 256 + ss * 64 + c) * 9 + k];
        ws[WEFF2 + tid] = s;
    }
    if (tid < 108) {
        int g = tid / 27, j = tid % 27;
        ws[BIAS2 + tid] = b_offset[off_chan(g, j)];
    }
    if (tid < 128) ws[STATS + tid] = 0.f;
}

// fused: offset-conv (27 ch for this group) + sigmoid + bilinear gather + dcn GEMM
// + pixel-shuffle f32 store + per-channel stats.  grid: (64 tiles, g=4, b=2), 256 thr
__global__ void dcn_fused(const float* __restrict__ x, const float* __restrict__ ws,
                          float* __restrict__ out, float* __restrict__ stats) {
    int tile = blockIdx.x;
    int g = blockIdx.y;
    int b = blockIdx.z;
    int t = threadIdx.x;
    int h = (tile >> 3) * 16 + (t >> 4);
    int w = (tile & 7) * 16 + (t & 15);
    const float* xb = x + b * CH * HW;

    // ---- offset conv: 27 outputs for this group ----
    float oacc[27];
    const float* bp = ws + BIAS2 + g * 27;
#pragma unroll
    for (int j = 0; j < 27; ++j) oacc[j] = bp[j];

    int offs[9];
    float vmask[9];
#pragma unroll
    for (int k = 0; k < 9; ++k) {
        int yy = h + k / 3 - 1, xx = w + k % 3 - 1;
        bool v = (yy >= 0) && (yy < HH) && (xx >= 0) && (xx < WW);
        vmask[k] = v ? 1.f : 0.f;
        offs[k] = min(max(yy, 0), HH - 1) * WW + min(max(xx, 0), WW - 1);
    }

    const float* wp0 = ws + WEFF2 + (g * 64) * 243;   // 9*27 per channel
    for (int c = 0; c < CH; ++c) {
        const float* xp = xb + c * HW;
        float xr[9];
#pragma unroll
        for (int k = 0; k < 9; ++k) xr[k] = xp[offs[k]] * vmask[k];
        const float* wp = wp0 + c * 243;
#pragma unroll
        for (int k = 0; k < 9; ++k)
#pragma unroll
            for (int j = 0; j < 27; ++j)
                oacc[j] = fmaf(xr[k], wp[k * 27 + j], oacc[j]);
    }

    // ---- deformable conv ----
    float acc[64];
#pragma unroll
    for (int o = 0; o < 64; ++o) acc[o] = 0.f;

    for (int k = 0; k < 9; ++k) {
        float dy = oacc[2 * k];
        float dx = oacc[2 * k + 1];
        float mk = 1.f / (1.f + expf(-oacc[18 + k]));

        float py = (float)h + (float)(k / 3 - 1) + dy;
        float qx = (float)w + (float)(k % 3 - 1) + dx;
        float y0f = floorf(py), x0f = floorf(qx);
        float ly = py - y0f, lx = qx - x0f;
        int y0 = (int)y0f, x0 = (int)x0f;
        int y1 = y0 + 1, x1 = x0 + 1;

        bool vy0 = (y0 >= 0) && (y0 < HH), vy1 = (y1 >= 0) && (y1 < HH);
        bool vx0 = (x0 >= 0) && (x0 < WW), vx1 = (x1 >= 0) && (x1 < WW);
        int yc0 = min(max(y0, 0), HH - 1), yc1 = min(max(y1, 0), HH - 1);
        int xc0 = min(max(x0, 0), WW - 1), xc1 = min(max(x1, 0), WW - 1);
        int i00 = yc0 * WW + xc0, i01 = yc0 * WW + xc1;
        int i10 = yc1 * WW + xc0, i11 = yc1 * WW + xc1;

        float w00 = (1.f - ly) * (1.f - lx) * mk * ((vy0 && vx0) ? 1.f : 0.f);
        float w01 = (1.f - ly) * lx * mk * ((vy0 && vx1) ? 1.f : 0.f);
        float w10 = ly * (1.f - lx) * mk * ((vy1 && vx0) ? 1.f : 0.f);
        float w11 = ly * lx * mk * ((vy1 && vx1) ? 1.f : 0.f);

        const float* wkp = ws + WTOFF + g * 36864 + k * 64;
        for (int c = 0; c < CH; ++c) {
            const float* xp = xb + c * HW;
            float col = w00 * xp[i00] + w01 * xp[i01] + w10 * xp[i10] + w11 * xp[i11];
            const float* wp = wkp + c * 576;
#pragma unroll
            for (int o = 0; o < 64; ++o) acc[o] = fmaf(col, wp[o], acc[o]);
        }
    }

    // ---- pixel shuffle store (pre-norm, f32) ----
    int h2 = h * 2 + (g >> 1), w2 = w * 2 + (g & 1);
    float* ob = out + (size_t)b * 64 * 65536 + (size_t)h2 * 256 + w2;
#pragma unroll
    for (int o = 0; o < 64; ++o)
        ob[(size_t)o * 65536] = acc[o];

    // ---- per-channel stats ----
    for (int o = 0; o < 64; ++o) {
        float v = acc[o];
        float v2 = v * v;
#pragma unroll
        for (int m = 32; m >= 1; m >>= 1) {
            v += __shfl_xor(v, m);
            v2 += __shfl_xor(v2, m);
        }
        if ((t & 63) == 0) {
            atomicAdd(stats + o, v);
            atomicAdd(stats + 64 + o, v2);
        }
    }
}

__global__ void finalize(const float* __restrict__ stats,
                         const float* __restrict__ gamma,
                         const float* __restrict__ beta,
                         float* __restrict__ ab) {
    int t = threadIdx.x;
    if (t < 64) {
        float mean = stats[t] / NVALS;
        float var = stats[64 + t] / NVALS - mean * mean;
        var = fmaxf(var, 0.f);
        float a = gamma[t] * rsqrtf(var + 1e-5f);
        ab[t] = a;
        ab[64 + t] = beta[t] - mean * a;
    }
}

// normalize + relu in place on f32 d_out; 4 floats per thread
__global__ void norm_relu(float* __restrict__ out, const float* __restrict__ ab) {
    size_t tid = (size_t)blockIdx.x * 256 + threadIdx.x;
    size_t base = tid * 4;
    int o = (int)((base >> 16) & 63);    // channel stride = 65536 elements
    float a = ab[o], bb = ab[64 + o];
    float4* p = (float4*)(out + base);
    float4 v = *p;
    v.x = fmaxf(fmaf(v.x, a, bb), 0.f);
    v.y = fmaxf(fmaf(v.y, a, bb), 0.f);
    v.z = fmaxf(fmaf(v.z, a, bb), 0.f);
    v.w = fmaxf(fmaf(v.w, a, bb), 0.f);
    *p = v;
}

extern "C" void kernel_launch(void* const* d_in, const int* in_sizes, int n_in,
                              void* d_out, int out_size, void* d_ws, size_t ws_size,
                              hipStream_t stream) {
    const float* x        = (const float*)d_in[0];
    const float* w_offset = (const float*)d_in[1];
    const float* b_offset = (const float*)d_in[2];
    const float* w_dcn    = (const float*)d_in[3];
    const float* gamma    = (const float*)d_in[4];
    const float* beta     = (const float*)d_in[5];
    float* out            = (float*)d_out;
    float* ws = (float*)d_ws;

    prep<<<576, 256, 0, stream>>>(w_offset, b_offset, w_dcn, ws);
    dcn_fused<<<dim3(64, 4, 2), 256, 0, stream>>>(x, ws, out, ws + STATS);
    finalize<<<1, 64, 0, stream>>>(ws + STATS, gamma, beta, ws + STATS + 128);
    norm_relu<<<8192, 256, 0, stream>>>(out, ws + STATS + 128);
}

// Round 4
// 1389.150 us; speedup vs baseline: 1.0012x; 1.0012x over previous
//
#include <hip/hip_runtime.h>
#include <math.h>

#define CH 64
#define HH 128
#define WW 128
#define HW 16384
#define NVALS 131072.f

// ws layout (floats):
//  weff2: ((g*64+c)*9+k)*27 + j   62208 floats
//  bias2: g*27 + j                  108 floats
//  wT:    g*36864 + c*576 + k*64+o 147456 floats
//  stats: sum[64] sumsq[64] a[64] b[64]  256 floats
#define WEFF2 0
#define BIAS2 62208
#define WTOFF 62464
#define STATS 209920

__device__ __forceinline__ int off_chan(int g, int j) {
    return (j < 18) ? (g * 18 + j) : (72 + g * 9 + (j - 18));
}

__global__ void prep(const float* __restrict__ w_offset, const float* __restrict__ b_offset,
                     const float* __restrict__ w_dcn, float* __restrict__ ws) {
    int tid = blockIdx.x * 256 + threadIdx.x;
    if (tid < 147456) {
        int o = tid & 63;
        int k = (tid >> 6) % 9;
        int c = (tid / 576) & 63;
        int g = tid / 36864;
        ws[WTOFF + tid] = w_dcn[((g * 64 + o) * 64 + c) * 9 + k];
    }
    if (tid < 62208) {
        int j = tid % 27;
        int r = tid / 27;
        int k = r % 9;
        int gc = r / 9;
        int c = gc & 63;
        int g = gc >> 6;
        int o = off_chan(g, j);
        float s = 0.f;
#pragma unroll
        for (int ss = 0; ss < 4; ++ss)
            s += w_offset[(o * 256 + ss * 64 + c) * 9 + k];
        ws[WEFF2 + tid] = s;
    }
    if (tid < 108) {
        int g = tid / 27, j = tid % 27;
        ws[BIAS2 + tid] = b_offset[off_chan(g, j)];
    }
    if (tid < 128) ws[STATS + tid] = 0.f;
}

// grid: (64 tiles of 16x16, g=4, b=2), 256 threads
__global__ __launch_bounds__(256) void dcn_fused(const float* __restrict__ x,
                                                 const float* __restrict__ ws,
                                                 float* __restrict__ out,
                                                 float* __restrict__ stats) {
    int tile = blockIdx.x;
    int g = blockIdx.y;
    int b = blockIdx.z;
    int t = threadIdx.x;
    int h = (tile >> 3) * 16 + (t >> 4);
    int w = (tile & 7) * 16 + (t & 15);
    const float* xb = x + b * CH * HW;

    // ---- offset conv: 27 outputs for this group ----
    float oacc[27];
    const float* bp = ws + BIAS2 + g * 27;
#pragma unroll
    for (int j = 0; j < 27; ++j) oacc[j] = bp[j];

    int offs[9];
    float vmask[9];
#pragma unroll
    for (int k = 0; k < 9; ++k) {
        int yy = h + k / 3 - 1, xx = w + k % 3 - 1;
        bool v = (yy >= 0) && (yy < HH) && (xx >= 0) && (xx < WW);
        vmask[k] = v ? 1.f : 0.f;
        offs[k] = min(max(yy, 0), HH - 1) * WW + min(max(xx, 0), WW - 1);
    }

    const float* wp0 = ws + WEFF2 + (g * 64) * 243;
    for (int c = 0; c < CH; ++c) {
        const float* xp = xb + c * HW;
        float xr[9];
#pragma unroll
        for (int k = 0; k < 9; ++k) xr[k] = xp[offs[k]] * vmask[k];
        const float* wp = wp0 + c * 243;
#pragma unroll
        for (int k = 0; k < 9; ++k)
#pragma unroll
            for (int j = 0; j < 27; ++j)
                oacc[j] = fmaf(xr[k], wp[k * 27 + j], oacc[j]);
    }

    // ---- bilinear setup: 36 (weight, index) pairs, k-only (fully unrolled!) ----
    float bw[36];
    int bidx[36];
#pragma unroll
    for (int k = 0; k < 9; ++k) {
        float dy = oacc[2 * k];
        float dx = oacc[2 * k + 1];
        float mk = 1.f / (1.f + expf(-oacc[18 + k]));

        float py = (float)h + (float)(k / 3 - 1) + dy;
        float qx = (float)w + (float)(k % 3 - 1) + dx;
        float y0f = floorf(py), x0f = floorf(qx);
        float ly = py - y0f, lx = qx - x0f;
        int y0 = (int)y0f, x0 = (int)x0f;
        int y1 = y0 + 1, x1 = x0 + 1;

        bool vy0 = (y0 >= 0) && (y0 < HH), vy1 = (y1 >= 0) && (y1 < HH);
        bool vx0 = (x0 >= 0) && (x0 < WW), vx1 = (x1 >= 0) && (x1 < WW);
        int yc0 = min(max(y0, 0), HH - 1), yc1 = min(max(y1, 0), HH - 1);
        int xc0 = min(max(x0, 0), WW - 1), xc1 = min(max(x1, 0), WW - 1);

        bidx[k * 4 + 0] = yc0 * WW + xc0;
        bidx[k * 4 + 1] = yc0 * WW + xc1;
        bidx[k * 4 + 2] = yc1 * WW + xc0;
        bidx[k * 4 + 3] = yc1 * WW + xc1;
        bw[k * 4 + 0] = (1.f - ly) * (1.f - lx) * mk * ((vy0 && vx0) ? 1.f : 0.f);
        bw[k * 4 + 1] = (1.f - ly) * lx * mk * ((vy0 && vx1) ? 1.f : 0.f);
        bw[k * 4 + 2] = ly * (1.f - lx) * mk * ((vy1 && vx0) ? 1.f : 0.f);
        bw[k * 4 + 3] = ly * lx * mk * ((vy1 && vx1) ? 1.f : 0.f);
    }

    // ---- main GEMM loop: c outer, all inner loops unrolled ----
    float acc[64];
#pragma unroll
    for (int o = 0; o < 64; ++o) acc[o] = 0.f;

    const float* wg = ws + WTOFF + g * 36864;
    for (int c = 0; c < CH; ++c) {
        const float* xp = xb + c * HW;
        float xv[36];
#pragma unroll
        for (int j = 0; j < 36; ++j) xv[j] = xp[bidx[j]];
        float col[9];
#pragma unroll
        for (int k = 0; k < 9; ++k)
            col[k] = bw[4 * k] * xv[4 * k] + bw[4 * k + 1] * xv[4 * k + 1]
                   + bw[4 * k + 2] * xv[4 * k + 2] + bw[4 * k + 3] * xv[4 * k + 3];
        const float* wp = wg + c * 576;   // [k][o], wave-uniform address -> scalar loads
#pragma unroll
        for (int k = 0; k < 9; ++k)
#pragma unroll
            for (int o = 0; o < 64; ++o)
                acc[o] = fmaf(col[k], wp[k * 64 + o], acc[o]);
    }

    // ---- pixel shuffle store (pre-norm, f32) ----
    int h2 = h * 2 + (g >> 1), w2 = w * 2 + (g & 1);
    float* ob = out + (size_t)b * 64 * 65536 + (size_t)h2 * 256 + w2;
#pragma unroll
    for (int o = 0; o < 64; ++o)
        ob[(size_t)o * 65536] = acc[o];

    // ---- per-channel stats (fully unrolled: keep acc in VGPRs) ----
#pragma unroll
    for (int o = 0; o < 64; ++o) {
        float v = acc[o];
        float v2 = v * v;
#pragma unroll
        for (int m = 32; m >= 1; m >>= 1) {
            v += __shfl_xor(v, m);
            v2 += __shfl_xor(v2, m);
        }
        if ((t & 63) == 0) {
            atomicAdd(stats + o, v);
            atomicAdd(stats + 64 + o, v2);
        }
    }
}

__global__ void finalize(const float* __restrict__ stats,
                         const float* __restrict__ gamma,
                         const float* __restrict__ beta,
                         float* __restrict__ ab) {
    int t = threadIdx.x;
    if (t < 64) {
        float mean = stats[t] / NVALS;
        float var = stats[64 + t] / NVALS - mean * mean;
        var = fmaxf(var, 0.f);
        float a = gamma[t] * rsqrtf(var + 1e-5f);
        ab[t] = a;
        ab[64 + t] = beta[t] - mean * a;
    }
}

__global__ void norm_relu(float* __restrict__ out, const float* __restrict__ ab) {
    size_t tid = (size_t)blockIdx.x * 256 + threadIdx.x;
    size_t base = tid * 4;
    int o = (int)((base >> 16) & 63);
    float a = ab[o], bb = ab[64 + o];
    float4* p = (float4*)(out + base);
    float4 v = *p;
    v.x = fmaxf(fmaf(v.x, a, bb), 0.f);
    v.y = fmaxf(fmaf(v.y, a, bb), 0.f);
    v.z = fmaxf(fmaf(v.z, a, bb), 0.f);
    v.w = fmaxf(fmaf(v.w, a, bb), 0.f);
    *p = v;
}

extern "C" void kernel_launch(void* const* d_in, const int* in_sizes, int n_in,
                              void* d_out, int out_size, void* d_ws, size_t ws_size,
                              hipStream_t stream) {
    const float* x        = (const float*)d_in[0];
    const float* w_offset = (const float*)d_in[1];
    const float* b_offset = (const float*)d_in[2];
    const float* w_dcn    = (const float*)d_in[3];
    const float* gamma    = (const float*)d_in[4];
    const float* beta     = (const float*)d_in[5];
    float* out            = (float*)d_out;
    float* ws = (float*)d_ws;

    prep<<<576, 256, 0, stream>>>(w_offset, b_offset, w_dcn, ws);
    dcn_fused<<<dim3(64, 4, 2), 256, 0, stream>>>(x, ws, out, ws + STATS);
    finalize<<<1, 64, 0, stream>>>(ws + STATS, gamma, beta, ws + STATS + 128);
    norm_relu<<<8192, 256, 0, stream>>>(out, ws + STATS + 128);
}

// Round 5
// 1249.701 us; speedup vs baseline: 1.1129x; 1.1116x over previous
//
#include <hip/hip_runtime.h>
#include <math.h>

#define CH 64
#define HH 128
#define WW 128
#define HW 16384
#define NVALS 131072.f

// ws layout (floats):
//  weff2: ((g*64+c)*9+k)*27 + j   62208 floats
//  bias2: g*27 + j                  108 floats
//  wT:    g*36864 + c*576 + k*64+o 147456 floats
//  stats: sum[64] sumsq[64] a[64] b[64]  256 floats
#define WEFF2 0
#define BIAS2 62208
#define WTOFF 62464
#define STATS 209920

__device__ __forceinline__ int off_chan(int g, int j) {
    return (j < 18) ? (g * 18 + j) : (72 + g * 9 + (j - 18));
}

__global__ void prep(const float* __restrict__ w_offset, const float* __restrict__ b_offset,
                     const float* __restrict__ w_dcn, float* __restrict__ ws) {
    int tid = blockIdx.x * 256 + threadIdx.x;
    if (tid < 147456) {
        int o = tid & 63;
        int k = (tid >> 6) % 9;
        int c = (tid / 576) & 63;
        int g = tid / 36864;
        ws[WTOFF + tid] = w_dcn[((g * 64 + o) * 64 + c) * 9 + k];
    }
    if (tid < 62208) {
        int j = tid % 27;
        int r = tid / 27;
        int k = r % 9;
        int gc = r / 9;
        int c = gc & 63;
        int g = gc >> 6;
        int o = off_chan(g, j);
        float s = 0.f;
#pragma unroll
        for (int ss = 0; ss < 4; ++ss)
            s += w_offset[(o * 256 + ss * 64 + c) * 9 + k];
        ws[WEFF2 + tid] = s;
    }
    if (tid < 108) {
        int g = tid / 27, j = tid % 27;
        ws[BIAS2 + tid] = b_offset[off_chan(g, j)];
    }
    if (tid < 128) ws[STATS + tid] = 0.f;
}

// grid: (64 tiles of 16x16, g=4, b=2), 256 threads
__global__ __launch_bounds__(256) void dcn_fused(const float* __restrict__ x,
                                                 const float* __restrict__ ws,
                                                 float* __restrict__ out,
                                                 float* __restrict__ stats) {
    int tile = blockIdx.x;
    int g = blockIdx.y;
    int b = blockIdx.z;
    int t = threadIdx.x;
    int h = (tile >> 3) * 16 + (t >> 4);
    int w = (tile & 7) * 16 + (t & 15);
    const float* xb = x + b * CH * HW;

    // ---- offset conv: 27 outputs for this group ----
    float oacc[27];
    const float* bp = ws + BIAS2 + g * 27;
#pragma unroll
    for (int j = 0; j < 27; ++j) oacc[j] = bp[j];

    {
        int offs[9];
        float vmask[9];
#pragma unroll
        for (int k = 0; k < 9; ++k) {
            int yy = h + k / 3 - 1, xx = w + k % 3 - 1;
            bool v = (yy >= 0) && (yy < HH) && (xx >= 0) && (xx < WW);
            vmask[k] = v ? 1.f : 0.f;
            offs[k] = min(max(yy, 0), HH - 1) * WW + min(max(xx, 0), WW - 1);
        }
        const float* wp0 = ws + WEFF2 + (g * 64) * 243;
        for (int c = 0; c < CH; ++c) {
            const float* xp = xb + c * HW;
            float xr[9];
#pragma unroll
            for (int k = 0; k < 9; ++k) xr[k] = xp[offs[k]] * vmask[k];
            const float* wp = wp0 + c * 243;
#pragma unroll
            for (int k = 0; k < 9; ++k)
#pragma unroll
                for (int j = 0; j < 27; ++j)
                    oacc[j] = fmaf(xr[k], wp[k * 27 + j], oacc[j]);
        }
    }

    // ---- deformable conv: k OUTER (recompute bilinear per k), c inner, spill-free ----
    float acc[64];
#pragma unroll
    for (int o = 0; o < 64; ++o) acc[o] = 0.f;

    const float* wg = ws + WTOFF + g * 36864;
#pragma unroll
    for (int k = 0; k < 9; ++k) {
        float dy = oacc[2 * k];
        float dx = oacc[2 * k + 1];
        float mk = 1.f / (1.f + expf(-oacc[18 + k]));

        float py = (float)h + (float)(k / 3 - 1) + dy;
        float qx = (float)w + (float)(k % 3 - 1) + dx;
        float y0f = floorf(py), x0f = floorf(qx);
        float ly = py - y0f, lx = qx - x0f;
        int y0 = (int)y0f, x0 = (int)x0f;
        int y1 = y0 + 1, x1 = x0 + 1;

        bool vy0 = (y0 >= 0) && (y0 < HH), vy1 = (y1 >= 0) && (y1 < HH);
        bool vx0 = (x0 >= 0) && (x0 < WW), vx1 = (x1 >= 0) && (x1 < WW);
        int yc0 = min(max(y0, 0), HH - 1), yc1 = min(max(y1, 0), HH - 1);
        int xc0 = min(max(x0, 0), WW - 1), xc1 = min(max(x1, 0), WW - 1);
        int i00 = yc0 * WW + xc0, i01 = yc0 * WW + xc1;
        int i10 = yc1 * WW + xc0, i11 = yc1 * WW + xc1;

        float w00 = (1.f - ly) * (1.f - lx) * mk * ((vy0 && vx0) ? 1.f : 0.f);
        float w01 = (1.f - ly) * lx * mk * ((vy0 && vx1) ? 1.f : 0.f);
        float w10 = ly * (1.f - lx) * mk * ((vy1 && vx0) ? 1.f : 0.f);
        float w11 = ly * lx * mk * ((vy1 && vx1) ? 1.f : 0.f);

        const float* wk = wg + k * 64;
#pragma unroll 2
        for (int c = 0; c < CH; ++c) {
            const float* xp = xb + c * HW;
            float col = w00 * xp[i00] + w01 * xp[i01] + w10 * xp[i10] + w11 * xp[i11];
            const float* wp = wk + c * 576;   // wave-uniform -> scalar loads
#pragma unroll
            for (int o = 0; o < 64; ++o)
                acc[o] = fmaf(col, wp[o], acc[o]);
        }
    }

    // ---- pixel shuffle store (pre-norm, f32) ----
    int h2 = h * 2 + (g >> 1), w2 = w * 2 + (g & 1);
    float* ob = out + (size_t)b * 64 * 65536 + (size_t)h2 * 256 + w2;
#pragma unroll
    for (int o = 0; o < 64; ++o)
        ob[(size_t)o * 65536] = acc[o];

    // ---- per-channel stats (fully unrolled; acc in VGPRs) ----
#pragma unroll
    for (int o = 0; o < 64; ++o) {
        float v = acc[o];
        float v2 = v * v;
#pragma unroll
        for (int m = 32; m >= 1; m >>= 1) {
            v += __shfl_xor(v, m);
            v2 += __shfl_xor(v2, m);
        }
        if ((t & 63) == 0) {
            atomicAdd(stats + o, v);
            atomicAdd(stats + 64 + o, v2);
        }
    }
}

__global__ void finalize(const float* __restrict__ stats,
                         const float* __restrict__ gamma,
                         const float* __restrict__ beta,
                         float* __restrict__ ab) {
    int t = threadIdx.x;
    if (t < 64) {
        float mean = stats[t] / NVALS;
        float var = stats[64 + t] / NVALS - mean * mean;
        var = fmaxf(var, 0.f);
        float a = gamma[t] * rsqrtf(var + 1e-5f);
        ab[t] = a;
        ab[64 + t] = beta[t] - mean * a;
    }
}

__global__ void norm_relu(float* __restrict__ out, const float* __restrict__ ab) {
    size_t tid = (size_t)blockIdx.x * 256 + threadIdx.x;
    size_t base = tid * 4;
    int o = (int)((base >> 16) & 63);
    float a = ab[o], bb = ab[64 + o];
    float4* p = (float4*)(out + base);
    float4 v = *p;
    v.x = fmaxf(fmaf(v.x, a, bb), 0.f);
    v.y = fmaxf(fmaf(v.y, a, bb), 0.f);
    v.z = fmaxf(fmaf(v.z, a, bb), 0.f);
    v.w = fmaxf(fmaf(v.w, a, bb), 0.f);
    *p = v;
}

extern "C" void kernel_launch(void* const* d_in, const int* in_sizes, int n_in,
                              void* d_out, int out_size, void* d_ws, size_t ws_size,
                              hipStream_t stream) {
    const float* x        = (const float*)d_in[0];
    const float* w_offset = (const float*)d_in[1];
    const float* b_offset = (const float*)d_in[2];
    const float* w_dcn    = (const float*)d_in[3];
    const float* gamma    = (const float*)d_in[4];
    const float* beta     = (const float*)d_in[5];
    float* out            = (float*)d_out;
    float* ws = (float*)d_ws;

    prep<<<576, 256, 0, stream>>>(w_offset, b_offset, w_dcn, ws);
    dcn_fused<<<dim3(64, 4, 2), 256, 0, stream>>>(x, ws, out, ws + STATS);
    finalize<<<1, 64, 0, stream>>>(ws + STATS, gamma, beta, ws + STATS + 128);
    norm_relu<<<8192, 256, 0, stream>>>(out, ws + STATS + 128);
}

// Round 6
// 1249.130 us; speedup vs baseline: 1.1134x; 1.0005x over previous
//
#include <hip/hip_runtime.h>
#include <math.h>

#define CH 64
#define HH 128
#define WW 128
#define HW 16384
#define NVALS 131072.f

// ws layout (floats):
//  weff2: ((g*64+c)*9+k)*27 + j   62208 floats
//  bias2: g*27 + j                  108 floats
//  wT:    g*36864 + c*576 + k*64+o 147456 floats
//  stats: sum[64] sumsq[64] a[64] b[64]  256 floats
//  oacc:  ((b*4+g)*27+j)*16384+px  3538944 floats
#define WEFF2 0
#define BIAS2 62208
#define WTOFF 62464
#define STATS 209920
#define OACC  210176

__device__ __forceinline__ int off_chan(int g, int j) {
    return (j < 18) ? (g * 18 + j) : (72 + g * 9 + (j - 18));
}

__global__ void prep(const float* __restrict__ w_offset, const float* __restrict__ b_offset,
                     const float* __restrict__ w_dcn, float* __restrict__ ws) {
    int tid = blockIdx.x * 256 + threadIdx.x;
    if (tid < 147456) {
        int o = tid & 63;
        int k = (tid >> 6) % 9;
        int c = (tid / 576) & 63;
        int g = tid / 36864;
        ws[WTOFF + tid] = w_dcn[((g * 64 + o) * 64 + c) * 9 + k];
    }
    if (tid < 62208) {
        int j = tid % 27;
        int r = tid / 27;
        int k = r % 9;
        int gc = r / 9;
        int c = gc & 63;
        int g = gc >> 6;
        int o = off_chan(g, j);
        float s = 0.f;
#pragma unroll
        for (int ss = 0; ss < 4; ++ss)
            s += w_offset[(o * 256 + ss * 64 + c) * 9 + k];
        ws[WEFF2 + tid] = s;
    }
    if (tid < 108) {
        int g = tid / 27, j = tid % 27;
        ws[BIAS2 + tid] = b_offset[off_chan(g, j)];
    }
    if (tid < 128) ws[STATS + tid] = 0.f;
}

// offset conv, j-chunked by template.  grid (64 tiles, g=4, b=2), 256 thr
template <int JBASE, int JN>
__global__ __launch_bounds__(256, 4) void conv_off(const float* __restrict__ x,
                                                   float* __restrict__ ws) {
    int tile = blockIdx.x;
    int g = blockIdx.y;
    int b = blockIdx.z;
    int t = threadIdx.x;
    int h = (tile >> 3) * 16 + (t >> 4);
    int w = (tile & 7) * 16 + (t & 15);
    const float* xb = x + b * CH * HW;

    float oacc[JN];
    const float* bp = ws + BIAS2 + g * 27 + JBASE;
#pragma unroll
    for (int j = 0; j < JN; ++j) oacc[j] = bp[j];

    int offs[9];
    float vmask[9];
#pragma unroll
    for (int k = 0; k < 9; ++k) {
        int yy = h + k / 3 - 1, xx = w + k % 3 - 1;
        bool v = (yy >= 0) && (yy < HH) && (xx >= 0) && (xx < WW);
        vmask[k] = v ? 1.f : 0.f;
        offs[k] = min(max(yy, 0), HH - 1) * WW + min(max(xx, 0), WW - 1);
    }

    const float* wp0 = ws + WEFF2 + (g * 64) * 243 + JBASE;
    for (int c = 0; c < CH; ++c) {
        const float* xp = xb + c * HW;
        float xr[9];
#pragma unroll
        for (int k = 0; k < 9; ++k) xr[k] = xp[offs[k]] * vmask[k];
        const float* wp = wp0 + c * 243;
#pragma unroll
        for (int k = 0; k < 9; ++k)
#pragma unroll
            for (int j = 0; j < JN; ++j)
                oacc[j] = fmaf(xr[k], wp[k * 27 + j], oacc[j]);
    }

    float* op = ws + OACC + (size_t)((b * 4 + g) * 27 + JBASE) * HW + h * WW + w;
#pragma unroll
    for (int j = 0; j < JN; ++j) op[(size_t)j * HW] = oacc[j];
}

// deformable conv, o-chunked (32/block).  grid (64 tiles, g=4, b*2+ohalf=4), 256 thr
__global__ __launch_bounds__(256, 4) void dcn(const float* __restrict__ x,
                                              const float* __restrict__ ws,
                                              float* __restrict__ out,
                                              float* __restrict__ stats) {
    int tile = blockIdx.x;
    int g = blockIdx.y;
    int b = blockIdx.z >> 1;
    int obase = (blockIdx.z & 1) * 32;
    int t = threadIdx.x;
    int h = (tile >> 3) * 16 + (t >> 4);
    int w = (tile & 7) * 16 + (t & 15);
    int px = h * WW + w;
    const float* xb = x + b * CH * HW;
    const float* ob_in = ws + OACC + (size_t)(b * 4 + g) * 27 * HW + px;

    float acc[32];
#pragma unroll
    for (int o = 0; o < 32; ++o) acc[o] = 0.f;

    const float* wg = ws + WTOFF + g * 36864 + obase;
#pragma unroll
    for (int k = 0; k < 9; ++k) {
        float dy = ob_in[(size_t)(2 * k) * HW];
        float dx = ob_in[(size_t)(2 * k + 1) * HW];
        float mk = 1.f / (1.f + expf(-ob_in[(size_t)(18 + k) * HW]));

        float py = (float)h + (float)(k / 3 - 1) + dy;
        float qx = (float)w + (float)(k % 3 - 1) + dx;
        float y0f = floorf(py), x0f = floorf(qx);
        float ly = py - y0f, lx = qx - x0f;
        int y0 = (int)y0f, x0 = (int)x0f;
        int y1 = y0 + 1, x1 = x0 + 1;

        bool vy0 = (y0 >= 0) && (y0 < HH), vy1 = (y1 >= 0) && (y1 < HH);
        bool vx0 = (x0 >= 0) && (x0 < WW), vx1 = (x1 >= 0) && (x1 < WW);
        int yc0 = min(max(y0, 0), HH - 1), yc1 = min(max(y1, 0), HH - 1);
        int xc0 = min(max(x0, 0), WW - 1), xc1 = min(max(x1, 0), WW - 1);
        int i00 = yc0 * WW + xc0, i01 = yc0 * WW + xc1;
        int i10 = yc1 * WW + xc0, i11 = yc1 * WW + xc1;

        float w00 = (1.f - ly) * (1.f - lx) * mk * ((vy0 && vx0) ? 1.f : 0.f);
        float w01 = (1.f - ly) * lx * mk * ((vy0 && vx1) ? 1.f : 0.f);
        float w10 = ly * (1.f - lx) * mk * ((vy1 && vx0) ? 1.f : 0.f);
        float w11 = ly * lx * mk * ((vy1 && vx1) ? 1.f : 0.f);

        const float* wk = wg + k * 64;
#pragma unroll 2
        for (int c = 0; c < CH; ++c) {
            const float* xp = xb + c * HW;
            float col = w00 * xp[i00] + w01 * xp[i01] + w10 * xp[i10] + w11 * xp[i11];
            const float* wp = wk + c * 576;   // wave-uniform -> scalar loads
#pragma unroll
            for (int o = 0; o < 32; ++o)
                acc[o] = fmaf(col, wp[o], acc[o]);
        }
    }

    int h2 = h * 2 + (g >> 1), w2 = w * 2 + (g & 1);
    float* op = out + (size_t)b * 64 * 65536 + (size_t)obase * 65536
              + (size_t)h2 * 256 + w2;
#pragma unroll
    for (int o = 0; o < 32; ++o)
        op[(size_t)o * 65536] = acc[o];

#pragma unroll
    for (int o = 0; o < 32; ++o) {
        float v = acc[o];
        float v2 = v * v;
#pragma unroll
        for (int m = 32; m >= 1; m >>= 1) {
            v += __shfl_xor(v, m);
            v2 += __shfl_xor(v2, m);
        }
        if ((t & 63) == 0) {
            atomicAdd(stats + obase + o, v);
            atomicAdd(stats + 64 + obase + o, v2);
        }
    }
}

__global__ void finalize(const float* __restrict__ stats,
                         const float* __restrict__ gamma,
                         const float* __restrict__ beta,
                         float* __restrict__ ab) {
    int t = threadIdx.x;
    if (t < 64) {
        float mean = stats[t] / NVALS;
        float var = stats[64 + t] / NVALS - mean * mean;
        var = fmaxf(var, 0.f);
        float a = gamma[t] * rsqrtf(var + 1e-5f);
        ab[t] = a;
        ab[64 + t] = beta[t] - mean * a;
    }
}

__global__ void norm_relu(float* __restrict__ out, const float* __restrict__ ab) {
    size_t tid = (size_t)blockIdx.x * 256 + threadIdx.x;
    size_t base = tid * 4;
    int o = (int)((base >> 16) & 63);
    float a = ab[o], bb = ab[64 + o];
    float4* p = (float4*)(out + base);
    float4 v = *p;
    v.x = fmaxf(fmaf(v.x, a, bb), 0.f);
    v.y = fmaxf(fmaf(v.y, a, bb), 0.f);
    v.z = fmaxf(fmaf(v.z, a, bb), 0.f);
    v.w = fmaxf(fmaf(v.w, a, bb), 0.f);
    *p = v;
}

extern "C" void kernel_launch(void* const* d_in, const int* in_sizes, int n_in,
                              void* d_out, int out_size, void* d_ws, size_t ws_size,
                              hipStream_t stream) {
    const float* x        = (const float*)d_in[0];
    const float* w_offset = (const float*)d_in[1];
    const float* b_offset = (const float*)d_in[2];
    const float* w_dcn    = (const float*)d_in[3];
    const float* gamma    = (const float*)d_in[4];
    const float* beta     = (const float*)d_in[5];
    float* out            = (float*)d_out;
    float* ws = (float*)d_ws;

    prep<<<576, 256, 0, stream>>>(w_offset, b_offset, w_dcn, ws);
    conv_off<0, 14><<<dim3(64, 4, 2), 256, 0, stream>>>(x, ws);
    conv_off<14, 13><<<dim3(64, 4, 2), 256, 0, stream>>>(x, ws);
    dcn<<<dim3(64, 4, 4), 256, 0, stream>>>(x, ws, out, ws + STATS);
    finalize<<<1, 64, 0, stream>>>(ws + STATS, gamma, beta, ws + STATS + 128);
    norm_relu<<<8192, 256, 0, stream>>>(out, ws + STATS + 128);
}